// Round 11
// baseline (246.544 us; speedup 1.0000x reference)
//
#include <hip/hip_runtime.h>

typedef unsigned short ushort_t;
typedef __attribute__((ext_vector_type(8))) short short8;   // 8 x bf16 (MFMA A/B frag)
typedef __attribute__((ext_vector_type(4))) float floatx4;  // MFMA C/D frag

// Problem constants: N=4000, E=60000, M=16, C=64, H=64, HEADS=8, A=8, VC=8, CE=32, Z=90
// cmp (fp32, per role stride RS): WeWa [32*64] @8192, WeWvWo [32*8] @11264
// packW (ushort, 18432): W frags [mat r0S,r0T,r1S,r1T][(t*2+kh)][lane][j 0..7]
//                        + P frags @16384: [Ps/Pt][kh][lane][j]
constexpr int RS = 11520;

__device__ inline float bf2f(ushort_t u) {
    union { unsigned int i; float f; } v; v.i = ((unsigned int)u) << 16; return v.f;
}
__device__ inline ushort_t f2bf(float f) {
    union { float f; unsigned int i; } v; v.f = f;
    unsigned int b = v.i + 0x7FFFu + ((v.i >> 16) & 1u);  // RNE
    return (ushort_t)(b >> 16);
}
__device__ inline void st4(ushort_t* dst, const floatx4& c) {
    uint2 v;
    v.x = (unsigned int)f2bf(c[0]) | ((unsigned int)f2bf(c[1]) << 16);
    v.y = (unsigned int)f2bf(c[2]) | ((unsigned int)f2bf(c[3]) << 16);
    *(uint2*)dst = v;
}

#define MFMA(a, b, c) __builtin_amdgcn_mfma_f32_16x16x32_bf16((a), (b), (c), 0, 0, 0)

// ---------------------------------------------------------------------------
// Kernel 1: weight composites (blocks 0..47) || zero binCnt (blocks 48..)
// ---------------------------------------------------------------------------
__global__ __launch_bounds__(256) void k_prep(
    const float* __restrict__ Ws0, const float* __restrict__ Wt0, const float* __restrict__ We0,
    const float* __restrict__ Wa0, const float* __restrict__ Wv0, const float* __restrict__ Wo0,
    const float* __restrict__ Ws1, const float* __restrict__ Wt1, const float* __restrict__ We1,
    const float* __restrict__ Wa1, const float* __restrict__ Wv1, const float* __restrict__ Wo1,
    float* __restrict__ cmp, ushort_t* __restrict__ packW, int* __restrict__ binCnt, int N)
{
    int b = blockIdx.x;
    if (b >= 48) {
        int i = (b - 48) * 256 + threadIdx.x;
        if (i < N) binCnt[i] = 0;
        return;
    }
    int task = b % 6, r = (b / 6) % 2, z = b / 12;
    const float* Ws = r ? Ws1 : Ws0;
    const float* Wt = r ? Wt1 : Wt0;
    const float* We = r ? We1 : We0;
    const float* Wa = r ? Wa1 : Wa0;
    const float* Wv = r ? Wv1 : Wv0;
    const float* Wo = r ? Wo1 : Wo0;
    float* base = cmp + r * RS;

    if (task == 0 || task == 1) {
        // WsWa / WtWa -> fragment-packed bf16 only
        const float* L = task ? Wt : Ws;
        ushort_t* pw = packW + (r * 2 + task) * 4096;
        int lo = z * 1024;
        for (int idx = lo + threadIdx.x; idx < lo + 1024; idx += 256) {
            int c = idx >> 6, jc = idx & 63;
            float a = 0.f;
            #pragma unroll 8
            for (int k = 0; k < 64; ++k) a += L[c * 64 + k] * Wa[k * 64 + jc];
            int t = jc >> 4, n = jc & 15, kh = c >> 5, q = (c >> 3) & 3, jj = c & 7;
            pw[((t * 2 + kh) * 64 + q * 16 + n) * 8 + jj] = f2bf(a);
        }
    } else if (task == 2) {
        float* out = base + 8192;                       // WeWa linear fp32
        int lo = z * 512;
        for (int idx = lo + threadIdx.x; idx < lo + 512; idx += 256) {
            int ce = idx >> 6, jc = idx & 63;
            float a = 0.f;
            #pragma unroll 8
            for (int k = 0; k < 64; ++k) a += We[ce * 64 + k] * Wa[k * 64 + jc];
            out[idx] = a;
        }
    } else if (z == 0) {
        if (task == 5) {
            float* out = base + 11264;                  // WeWvWo linear fp32
            for (int idx = threadIdx.x; idx < 32 * 8; idx += 256) {
                int c = idx >> 3, h = idx & 7;
                float a = 0.f;
                for (int k = 0; k < 64; ++k) {
                    float wv = 0.f;
                    #pragma unroll
                    for (int aa = 0; aa < 8; ++aa) wv += Wv[k * 64 + h * 8 + aa] * Wo[h * 8 + aa];
                    a += We[c * 64 + k] * wv;
                }
                out[idx] = a;
            }
        } else {
            // task 3 (Ps) / 4 (Pt): write packed B-frags directly
            const float* L = (task == 3) ? Ws : Wt;
            ushort_t* pp = packW + 16384 + (task - 3) * 1024;
            for (int idx = threadIdx.x; idx < 64 * 8; idx += 256) {
                int c = idx >> 3, h = idx & 7;
                float a = 0.f;
                for (int k = 0; k < 64; ++k) {
                    float wv = 0.f;
                    #pragma unroll
                    for (int aa = 0; aa < 8; ++aa) wv += Wv[k * 64 + h * 8 + aa] * Wo[h * 8 + aa];
                    a += L[c * 64 + k] * wv;
                }
                int kh = c >> 5, q = (c >> 3) & 3, jj = c & 7;
                pp[kh * 512 + (q * 16 + r * 8 + h) * 8 + jj] = f2bf(a);
            }
        }
    }
}

// ---------------------------------------------------------------------------
// Kernel 2: per-node MFMA precompute (blocks < nodeBlocks, one wave/node) ||
// dst histogram (blocks >= nodeBlocks). Weights staged in 36 KB LDS.
// srcA/tgtA stored TRANSPOSED [64 cols][16 rows] bf16 per (node,role).
// Also zeroes den/num (no memset dispatch).
// ---------------------------------------------------------------------------
__global__ __launch_bounds__(256, 4) void k_node_hist(
    const float* __restrict__ x, const int* __restrict__ mask,
    const ushort_t* __restrict__ packW,
    float* __restrict__ psrc, float* __restrict__ ptgt,
    ushort_t* __restrict__ srcA, ushort_t* __restrict__ tgtA,
    float* __restrict__ den, float* __restrict__ num,
    const int* __restrict__ ei, int* __restrict__ binCnt,
    int N, int nodeBlocks, int E)
{
    if (blockIdx.x >= nodeBlocks) {
        int e = (blockIdx.x - nodeBlocks) * 256 + threadIdx.x;
        if (e < E) atomicAdd(&binCnt[ei[E + e]], 1);
        return;
    }

    __shared__ __align__(16) ushort_t lw[18432];   // 36 KB
    for (int i = threadIdx.x; i < 2304; i += 256)
        ((short8*)lw)[i] = ((const short8*)packW)[i];
    __syncthreads();

    int wid  = (int)((blockIdx.x * blockDim.x + threadIdx.x) >> 6);
    int lane = threadIdx.x & 63;
    int q    = lane >> 4;     // quad 0..3
    int n16  = lane & 15;     // 0..15

    if (wid < N) {
        int nd = wid;
        if (lane < 8)  den[nd * 8 + lane] = 0.f;
        if (lane < 24) num[nd * 24 + lane] = 0.f;

        const float* xp = x + (size_t)nd * 1024 + n16 * 64 + q * 8;
        float4 v0 = *(const float4*)(xp);
        float4 v1 = *(const float4*)(xp + 4);
        float4 v2 = *(const float4*)(xp + 32);
        float4 v3 = *(const float4*)(xp + 36);
        short8 a0, a1;
        a0[0] = (short)f2bf(v0.x); a0[1] = (short)f2bf(v0.y);
        a0[2] = (short)f2bf(v0.z); a0[3] = (short)f2bf(v0.w);
        a0[4] = (short)f2bf(v1.x); a0[5] = (short)f2bf(v1.y);
        a0[6] = (short)f2bf(v1.z); a0[7] = (short)f2bf(v1.w);
        a1[0] = (short)f2bf(v2.x); a1[1] = (short)f2bf(v2.y);
        a1[2] = (short)f2bf(v2.z); a1[3] = (short)f2bf(v2.w);
        a1[4] = (short)f2bf(v3.x); a1[5] = (short)f2bf(v3.y);
        a1[6] = (short)f2bf(v3.z); a1[7] = (short)f2bf(v3.w);

        int rsel = (mask[nd] != 0);
        const floatx4 zero = {0.f, 0.f, 0.f, 0.f};

        #define WF(mat, t, kh) (*(const short8*)&lw[(mat) * 4096 + ((t) * 2 + (kh)) * 512 + lane * 8])
        #define PF(m, kh)      (*(const short8*)&lw[16384 + (m) * 1024 + (kh) * 512 + lane * 8])

        {   // srcA role0 (mat 0)
            floatx4 c0 = zero, c1 = zero, c2 = zero, c3 = zero;
            c0 = MFMA(a0, WF(0,0,0), c0); c0 = MFMA(a1, WF(0,0,1), c0);
            c1 = MFMA(a0, WF(0,1,0), c1); c1 = MFMA(a1, WF(0,1,1), c1);
            c2 = MFMA(a0, WF(0,2,0), c2); c2 = MFMA(a1, WF(0,2,1), c2);
            c3 = MFMA(a0, WF(0,3,0), c3); c3 = MFMA(a1, WF(0,3,1), c3);
            ushort_t* sp = srcA + (size_t)nd * 2048 + n16 * 16 + q * 4;
            st4(sp, c0); st4(sp + 256, c1); st4(sp + 512, c2); st4(sp + 768, c3);
        }
        {   // srcA role1 (mat 2)
            floatx4 c0 = zero, c1 = zero, c2 = zero, c3 = zero;
            c0 = MFMA(a0, WF(2,0,0), c0); c0 = MFMA(a1, WF(2,0,1), c0);
            c1 = MFMA(a0, WF(2,1,0), c1); c1 = MFMA(a1, WF(2,1,1), c1);
            c2 = MFMA(a0, WF(2,2,0), c2); c2 = MFMA(a1, WF(2,2,1), c2);
            c3 = MFMA(a0, WF(2,3,0), c3); c3 = MFMA(a1, WF(2,3,1), c3);
            ushort_t* sp = srcA + (size_t)nd * 2048 + 1024 + n16 * 16 + q * 4;
            st4(sp, c0); st4(sp + 256, c1); st4(sp + 512, c2); st4(sp + 768, c3);
        }
        {   // tgtA selected role (mat 1 or 3) — wave-uniform branch
            int mt = rsel ? 3 : 1;
            floatx4 c0 = zero, c1 = zero, c2 = zero, c3 = zero;
            c0 = MFMA(a0, WF(mt,0,0), c0); c0 = MFMA(a1, WF(mt,0,1), c0);
            c1 = MFMA(a0, WF(mt,1,0), c1); c1 = MFMA(a1, WF(mt,1,1), c1);
            c2 = MFMA(a0, WF(mt,2,0), c2); c2 = MFMA(a1, WF(mt,2,1), c2);
            c3 = MFMA(a0, WF(mt,3,0), c3); c3 = MFMA(a1, WF(mt,3,1), c3);
            ushort_t* tp = tgtA + (size_t)nd * 1024 + n16 * 16 + q * 4;
            st4(tp, c0); st4(tp + 256, c1); st4(tp + 512, c2); st4(tp + 768, c3);
        }
        {   // Ps (both roles packed in cols) and Pt (selected role)
            floatx4 cp = zero;
            cp = MFMA(a0, PF(0,0), cp); cp = MFMA(a1, PF(0,1), cp);
            if (q == 0) {
                int r = n16 >> 3, h = n16 & 7;
                float* pp = psrc + (size_t)nd * 48 + r * 24 + h;
                pp[0]  = cp[1];
                pp[8]  = cp[2];
                pp[16] = cp[3];
            }
            floatx4 cq = zero;
            cq = MFMA(a0, PF(1,0), cq); cq = MFMA(a1, PF(1,1), cq);
            if (q == 0 && (n16 >> 3) == rsel) {
                int h = n16 & 7;
                float* pp = ptgt + (size_t)nd * 24 + h;
                pp[0]  = cq[1];
                pp[8]  = cq[2];
                pp[16] = cq[3];
            }
        }
        #undef WF
        #undef PF
    }
}

// ---------------------------------------------------------------------------
// Kernel 3: exclusive scan binCnt -> binPos cursor. 1 block.
// ---------------------------------------------------------------------------
__global__ __launch_bounds__(256) void k_scan(
    const int* __restrict__ binCnt, int* __restrict__ binPos, int N)
{
    __shared__ int part[256];
    int t = threadIdx.x;
    int chunk = (N + 255) / 256;
    int lo = t * chunk, hi = lo + chunk;
    if (lo > N) lo = N;
    if (hi > N) hi = N;
    int s = 0;
    for (int i = lo; i < hi; ++i) s += binCnt[i];
    part[t] = s;
    __syncthreads();
    for (int off = 1; off < 256; off <<= 1) {
        int v = (t >= off) ? part[t - off] : 0;
        __syncthreads();
        part[t] += v;
        __syncthreads();
    }
    int start = (t == 0) ? 0 : part[t - 1];
    for (int i = lo; i < hi; ++i) {
        int c = binCnt[i];
        binPos[i] = start;
        start += c;
    }
}

// ---------------------------------------------------------------------------
// Kernel 4: scatter edges into dst-sorted order[] (counting sort)
// ---------------------------------------------------------------------------
__global__ __launch_bounds__(256) void k_scatter(
    const int* __restrict__ ei, int* __restrict__ binPos,
    int* __restrict__ order, int E)
{
    int e = blockIdx.x * 256 + threadIdx.x;
    if (e < E) {
        int pos = atomicAdd(&binPos[ei[E + e]], 1);
        order[pos] = e;
    }
}

// ---------------------------------------------------------------------------
// Kernel C (fused): per-edge logits + exp + den/num scatter.
// R4-proven body (1 edge/wave, 256 thr, 44 VGPR) + dst-sorted order[] +
// XCD-CHUNKED block swizzle: blockIdx round-robins across the 8 XCDs
// (bid%8 = XCD), so mapping XCD x to a CONTIGUOUS chunk of the dst-sorted
// edge list keeps each dst's atomics AND its tgtA/ptgt slices inside ONE
// XCD's L2. This removes R5's failure mode (same-dst atomics from 8 XCDs
// ping-ponged lines: WRITE 7.5->367 MB) while keeping its locality win
// (R5 sustained 3.85 TB/s fabric BW).  Bijective m204 chunk formula.
// ---------------------------------------------------------------------------
__global__ __launch_bounds__(256) void k_fused(
    const int* __restrict__ ei, const float* __restrict__ dist,
    const int* __restrict__ zn, const int* __restrict__ mask,
    const float* __restrict__ wig, const float* __restrict__ cmp,
    const float* __restrict__ embs0, const float* __restrict__ embt0, const float* __restrict__ wd0,
    const float* __restrict__ embs1, const float* __restrict__ embt1, const float* __restrict__ wd1,
    const float* __restrict__ va0, const float* __restrict__ va1,
    const ushort_t* __restrict__ srcA, const ushort_t* __restrict__ tgtA,
    const float* __restrict__ psrc, const float* __restrict__ ptgt,
    const int* __restrict__ order,
    float* __restrict__ den, float* __restrict__ num, int E)
{
    int wv = threadIdx.x >> 6, j = threadIdx.x & 63;
    // XCD-chunked swizzle: hw block (x = bid%8 -> XCD, y-th on that XCD)
    // processes the y-th block of logical chunk x (contiguous dst range).
    int bid = blockIdx.x;
    int xx = bid & 7, yy = bid >> 3;
    int q8 = (int)(gridDim.x >> 3), r8 = (int)(gridDim.x & 7);
    int swz = (xx < r8 ? xx * (q8 + 1) : r8 * (q8 + 1) + (xx - r8) * q8) + yy;
    int el = swz * 4 + wv;
    if (el >= E) return;
    int e = order[el];

    int src = ei[e], dst = ei[E + e];
    int r = (mask[dst] != 0);
    float d = dist[e];
    int zs = zn[src], zt = zn[dst];
    int hq = j >> 3, h8 = j & 7;

    // issue all gathers up front (overlap latency with the ce loop)
    const float* w0 = wig + (size_t)e * 256;            // D[0, :]
    float4 wA = *(const float4*)(w0);
    float4 wB = *(const float4*)(w0 + 4);
    float4 wC = *(const float4*)(w0 + 8);
    float4 wD = *(const float4*)(w0 + 12);
    const ushort_t* sa = srcA + (size_t)src * 2048 + r * 1024 + j * 16;
    const ushort_t* ta = tgtA + (size_t)dst * 1024 + j * 16;
    short8 sv0 = *(const short8*)(sa);       // rows 0..7 of col j
    short8 sv1 = *(const short8*)(sa + 8);   // rows 8..15
    short8 tv0 = *(const short8*)(ta);
    short8 tv1 = *(const short8*)(ta + 8);
    float pv = 0.f;
    if (h8 < 3)
        pv = psrc[(size_t)src * 48 + r * 24 + h8 * 8 + hq]
           + ptgt[(size_t)dst * 24 + h8 * 8 + hq];

    // edge scalar embedding (32 values via j&31)
    float es;
    {
        int ce = j & 31;
        float z = r ? (d * wd1[ce] + embs1[zs * 32 + ce] + embt1[zt * 32 + ce])
                    : (d * wd0[ce] + embs0[zs * 32 + ce] + embt0[zt * 32 + ce]);
        es = z / (1.f + __expf(-z));   // silu
    }

    const float* WeWa   = cmp + r * RS + 8192;
    const float* WeWvWo = cmp + r * RS + 11264;
    float f0a = 0.f, ej = 0.f;
    #pragma unroll
    for (int ce = 0; ce < 32; ++ce) {
        float ev = __shfl(es, ce, 64);
        f0a += ev * WeWa[ce * 64 + j];
        ej  += ev * WeWvWo[ce * 8 + hq];
    }

    // f0a[j] += sum_n D[0,n] * (ysa[src][n,j] + yta[dst][n,j]) : in-lane
    f0a += wA.x * (bf2f((ushort_t)sv0[0]) + bf2f((ushort_t)tv0[0]));
    f0a += wA.y * (bf2f((ushort_t)sv0[1]) + bf2f((ushort_t)tv0[1]));
    f0a += wA.z * (bf2f((ushort_t)sv0[2]) + bf2f((ushort_t)tv0[2]));
    f0a += wA.w * (bf2f((ushort_t)sv0[3]) + bf2f((ushort_t)tv0[3]));
    f0a += wB.x * (bf2f((ushort_t)sv0[4]) + bf2f((ushort_t)tv0[4]));
    f0a += wB.y * (bf2f((ushort_t)sv0[5]) + bf2f((ushort_t)tv0[5]));
    f0a += wB.z * (bf2f((ushort_t)sv0[6]) + bf2f((ushort_t)tv0[6]));
    f0a += wB.w * (bf2f((ushort_t)sv0[7]) + bf2f((ushort_t)tv0[7]));
    f0a += wC.x * (bf2f((ushort_t)sv1[0]) + bf2f((ushort_t)tv1[0]));
    f0a += wC.y * (bf2f((ushort_t)sv1[1]) + bf2f((ushort_t)tv1[1]));
    f0a += wC.z * (bf2f((ushort_t)sv1[2]) + bf2f((ushort_t)tv1[2]));
    f0a += wC.w * (bf2f((ushort_t)sv1[3]) + bf2f((ushort_t)tv1[3]));
    f0a += wD.x * (bf2f((ushort_t)sv1[4]) + bf2f((ushort_t)tv1[4]));
    f0a += wD.y * (bf2f((ushort_t)sv1[5]) + bf2f((ushort_t)tv1[5]));
    f0a += wD.z * (bf2f((ushort_t)sv1[6]) + bf2f((ushort_t)tv1[6]));
    f0a += wD.w * (bf2f((ushort_t)sv1[7]) + bf2f((ushort_t)tv1[7]));

    float la = f0a > 0.f ? f0a : 0.2f * f0a;           // leaky_relu(0.2)
    float val = la * (r ? va1[j] : va0[j]);
    val += __shfl_xor(val, 1);
    val += __shfl_xor(val, 2);
    val += __shfl_xor(val, 4);                          // logit per 8-lane group
    float ex = __expf(val);                             // no-max softmax (logits bounded)

    if (h8 == 0) atomicAdd(&den[dst * 8 + hq], ex);
    if (h8 < 3) {
        float w0k = (h8 == 0) ? wA.y : (h8 == 1) ? wA.z : wA.w;  // D[0,1..3]
        atomicAdd(&num[dst * 24 + hq * 3 + h8], ex * (pv + ej * w0k));
    }
}

// ---------------------------------------------------------------------------
// Kernel D: out[n,k] = sum_h num[n,h,k]/(den[n,h]+eps). Writes every element.
// ---------------------------------------------------------------------------
__global__ __launch_bounds__(256) void k_out(
    const float* __restrict__ num, const float* __restrict__ den,
    float* __restrict__ out, int N3)
{
    int t = blockIdx.x * 256 + threadIdx.x;
    if (t >= N3) return;
    int n = t / 3, k = t - n * 3;
    float acc = 0.f;
    #pragma unroll
    for (int h = 0; h < 8; ++h)
        acc += num[n * 24 + h * 3 + k] / (den[n * 8 + h] + 1e-9f);
    out[t] = acc;
}

// ---------------------------------------------------------------------------
extern "C" void kernel_launch(void* const* d_in, const int* in_sizes, int n_in,
                              void* d_out, int out_size, void* d_ws, size_t ws_size,
                              hipStream_t stream) {
    const float* x    = (const float*)d_in[0];
    const int*   zn   = (const int*)d_in[1];
    const float* dist = (const float*)d_in[2];
    const int*   ei   = (const int*)d_in[3];
    const int*   mask = (const int*)d_in[4];
    const float* wig  = (const float*)d_in[5];
    // per role: emb_s, emb_t, w_d, We, Ws, Wt, Wa, va, Wv, Wo
    const float* fs[10]; const float* dn[10];
    for (int i = 0; i < 10; ++i) { fs[i] = (const float*)d_in[6 + i]; dn[i] = (const float*)d_in[16 + i]; }

    int N = in_sizes[1];   // atomic_numbers count
    int E = in_sizes[2];   // edge_distance count

    // workspace carve-up
    float* cmp  = (float*)d_ws;                    // 2*RS = 23040 floats
    float* den  = cmp + 2 * RS;                    // N*8
    float* num  = den + (size_t)N * 8;             // N*24
    float* psrc = num + (size_t)N * 24;            // N*48
    float* ptgt = psrc + (size_t)N * 48;           // N*24
    ushort_t* srcA = (ushort_t*)(ptgt + (size_t)N * 24);  // N*2048 bf16
    ushort_t* tgtA = srcA + (size_t)N * 2048;             // N*1024 bf16
    ushort_t* packW = tgtA + (size_t)N * 1024;            // 18432 ushorts (36 KB)
    int* binCnt = (int*)(packW + 18432);                  // N
    int* binPos = binCnt + N;                             // N
    int* order  = binPos + N;                             // E
    // total ~26.4 MB

    int zeroBlocks = (N + 255) / 256;
    k_prep<<<48 + zeroBlocks, 256, 0, stream>>>(
        fs[4], fs[5], fs[3], fs[6], fs[8], fs[9],
        dn[4], dn[5], dn[3], dn[6], dn[8], dn[9], cmp, packW, binCnt, N);

    int nodeBlocks = (N + 3) / 4;                 // one wave per node
    int histBlocks = (E + 255) / 256;
    k_node_hist<<<nodeBlocks + histBlocks, 256, 0, stream>>>(
        x, mask, packW, psrc, ptgt, srcA, tgtA, den, num, ei, binCnt,
        N, nodeBlocks, E);

    k_scan<<<1, 256, 0, stream>>>(binCnt, binPos, N);

    k_scatter<<<histBlocks, 256, 0, stream>>>(ei, binPos, order, E);

    k_fused<<<(E + 3) / 4, 256, 0, stream>>>(
        ei, dist, zn, mask, wig, cmp,
        fs[0], fs[1], fs[2], dn[0], dn[1], dn[2],
        fs[7], dn[7], srcA, tgtA, psrc, ptgt, order, den, num, E);

    k_out<<<(N * 3 + 255) / 256, 256, 0, stream>>>(num, den, (float*)d_out, N * 3);
}

// Round 12
// 224.276 us; speedup vs baseline: 1.0993x; 1.0993x over previous
//
#include <hip/hip_runtime.h>

typedef unsigned short ushort_t;
typedef __attribute__((ext_vector_type(8))) short short8;   // 8 x bf16 (MFMA A/B frag)
typedef __attribute__((ext_vector_type(4))) float floatx4;  // MFMA C/D frag

// Problem constants: N=4000, E=60000, M=16, C=64, H=64, HEADS=8, A=8, VC=8, CE=32, Z=90
// cmp (fp32, per role stride RS): WeWa [32*64] @8192, PsW @10240, PtW @10752,
// WeWvWo [32*8] @11264.  packW (ushort): [role][mat S/T][t][kh][lane][j]
constexpr int RS = 11520;

__device__ inline float bf2f(ushort_t u) {
    union { unsigned int i; float f; } v; v.i = ((unsigned int)u) << 16; return v.f;
}
__device__ inline ushort_t f2bf(float f) {
    union { float f; unsigned int i; } v; v.f = f;
    unsigned int b = v.i + 0x7FFFu + ((v.i >> 16) & 1u);  // RNE
    return (ushort_t)(b >> 16);
}
__device__ inline void st4(ushort_t* dst, const floatx4& c) {
    uint2 v;
    v.x = (unsigned int)f2bf(c[0]) | ((unsigned int)f2bf(c[1]) << 16);
    v.y = (unsigned int)f2bf(c[2]) | ((unsigned int)f2bf(c[3]) << 16);
    *(uint2*)dst = v;
}

#define MFMA(a, b, c) __builtin_amdgcn_mfma_f32_16x16x32_bf16((a), (b), (c), 0, 0, 0)

// ---------------------------------------------------------------------------
// Kernel A: weight composites.  grid = (6 tasks, 2 roles, 4 chunks), 256 thr
// ---------------------------------------------------------------------------
__global__ __launch_bounds__(256) void k_composites(
    const float* __restrict__ Ws0, const float* __restrict__ Wt0, const float* __restrict__ We0,
    const float* __restrict__ Wa0, const float* __restrict__ Wv0, const float* __restrict__ Wo0,
    const float* __restrict__ Ws1, const float* __restrict__ Wt1, const float* __restrict__ We1,
    const float* __restrict__ Wa1, const float* __restrict__ Wv1, const float* __restrict__ Wo1,
    float* __restrict__ cmp, ushort_t* __restrict__ packW)
{
    int task = blockIdx.x;   // 0..5
    int r    = blockIdx.y;   // 0..1
    int z    = blockIdx.z;   // 0..3
    const float* Ws = r ? Ws1 : Ws0;
    const float* Wt = r ? Wt1 : Wt0;
    const float* We = r ? We1 : We0;
    const float* Wa = r ? Wa1 : Wa0;
    const float* Wv = r ? Wv1 : Wv0;
    const float* Wo = r ? Wo1 : Wo0;
    float* base = cmp + r * RS;

    if (task == 0 || task == 1) {
        const float* L = task ? Wt : Ws;
        ushort_t* pw = packW + (r * 2 + task) * 4096;
        int lo = z * 1024;
        for (int idx = lo + threadIdx.x; idx < lo + 1024; idx += 256) {
            int c = idx >> 6, jc = idx & 63;
            float a = 0.f;
            #pragma unroll 8
            for (int k = 0; k < 64; ++k) a += L[c * 64 + k] * Wa[k * 64 + jc];
            int t = jc >> 4, n = jc & 15, kh = c >> 5, q = (c >> 3) & 3, jj = c & 7;
            pw[((t * 2 + kh) * 64 + q * 16 + n) * 8 + jj] = f2bf(a);
        }
    } else if (task == 2) {
        float* out = base + 8192;
        int lo = z * 512;
        for (int idx = lo + threadIdx.x; idx < lo + 512; idx += 256) {
            int ce = idx >> 6, jc = idx & 63;
            float a = 0.f;
            #pragma unroll 8
            for (int k = 0; k < 64; ++k) a += We[ce * 64 + k] * Wa[k * 64 + jc];
            out[idx] = a;
        }
    } else {
        if (z != 0) return;
        const float* L = (task == 3) ? Ws : (task == 4) ? Wt : We;
        int rows = (task == 5) ? 32 : 64;
        float* out = base + ((task == 3) ? 10240 : (task == 4) ? 10752 : 11264);
        for (int idx = threadIdx.x; idx < rows * 8; idx += 256) {
            int c = idx >> 3, h = idx & 7;
            float a = 0.f;
            for (int k = 0; k < 64; ++k) {
                float wv = 0.f;
                #pragma unroll
                for (int aa = 0; aa < 8; ++aa) wv += Wv[k * 64 + h * 8 + aa] * Wo[h * 8 + aa];
                a += L[c * 64 + k] * wv;
            }
            out[idx] = a;
        }
    }
}

// ---------------------------------------------------------------------------
// Kernel B: per-node MFMA precompute, one wave per node (R4-proven form).
// srcA/tgtA stored TRANSPOSED [64 cols][16 rows] bf16 per (node,role).
// Also zeroes den/num (no memset dispatch).
// ---------------------------------------------------------------------------
__device__ inline short8 bfragP(const float* __restrict__ P0, const float* __restrict__ P1,
                                int kBase, int q, int n) {
    const float* P = (n < 8) ? P0 : P1;
    int c = n & 7;
    short8 f;
    #pragma unroll
    for (int j = 0; j < 8; ++j)
        f[j] = (short)f2bf(P[(kBase + q * 8 + j) * 8 + c]);
    return f;
}

__global__ __launch_bounds__(256, 2) void k_node(
    const float* __restrict__ x, const int* __restrict__ mask,
    const float* __restrict__ cmp, const ushort_t* __restrict__ packW,
    float* __restrict__ psrc, float* __restrict__ ptgt,
    ushort_t* __restrict__ srcA, ushort_t* __restrict__ tgtA,
    float* __restrict__ den, float* __restrict__ num,
    int N, int totWaves)
{
    int wid  = (int)((blockIdx.x * blockDim.x + threadIdx.x) >> 6);
    int lane = threadIdx.x & 63;
    int q    = lane >> 4;
    int n16  = lane & 15;

    short8 Bs0[4][2], Bs1[4][2], Bt0[4][2], Bt1[4][2];
    #pragma unroll
    for (int t = 0; t < 4; ++t) {
        #pragma unroll
        for (int kh = 0; kh < 2; ++kh) {
            int fo = (t * 2 + kh) * 512 + lane * 8;
            Bs0[t][kh] = *(const short8*)(packW +           fo);
            Bt0[t][kh] = *(const short8*)(packW +  4096 +   fo);
            Bs1[t][kh] = *(const short8*)(packW +  8192 +   fo);
            Bt1[t][kh] = *(const short8*)(packW + 12288 +   fo);
        }
    }
    short8 Bp[2], Bq[2];
    #pragma unroll
    for (int kh = 0; kh < 2; ++kh) {
        Bp[kh] = bfragP(cmp + 10240, cmp + RS + 10240, kh * 32, q, n16);
        Bq[kh] = bfragP(cmp + 10752, cmp + RS + 10752, kh * 32, q, n16);
    }

    const floatx4 zero = {0.f, 0.f, 0.f, 0.f};

    for (int nd = wid; nd < N; nd += totWaves) {
        if (lane < 8)  den[nd * 8 + lane] = 0.f;
        if (lane < 24) num[nd * 24 + lane] = 0.f;

        const float* xp = x + (size_t)nd * 1024 + n16 * 64 + q * 8;
        float4 v0 = *(const float4*)(xp);
        float4 v1 = *(const float4*)(xp + 4);
        float4 v2 = *(const float4*)(xp + 32);
        float4 v3 = *(const float4*)(xp + 36);
        short8 a0, a1;
        a0[0] = (short)f2bf(v0.x); a0[1] = (short)f2bf(v0.y);
        a0[2] = (short)f2bf(v0.z); a0[3] = (short)f2bf(v0.w);
        a0[4] = (short)f2bf(v1.x); a0[5] = (short)f2bf(v1.y);
        a0[6] = (short)f2bf(v1.z); a0[7] = (short)f2bf(v1.w);
        a1[0] = (short)f2bf(v2.x); a1[1] = (short)f2bf(v2.y);
        a1[2] = (short)f2bf(v2.z); a1[3] = (short)f2bf(v2.w);
        a1[4] = (short)f2bf(v3.x); a1[5] = (short)f2bf(v3.y);
        a1[6] = (short)f2bf(v3.z); a1[7] = (short)f2bf(v3.w);

        int rsel = (mask[nd] != 0);

        {
            floatx4 c0 = zero, c1 = zero, c2 = zero, c3 = zero;
            c0 = MFMA(a0, Bs0[0][0], c0); c0 = MFMA(a1, Bs0[0][1], c0);
            c1 = MFMA(a0, Bs0[1][0], c1); c1 = MFMA(a1, Bs0[1][1], c1);
            c2 = MFMA(a0, Bs0[2][0], c2); c2 = MFMA(a1, Bs0[2][1], c2);
            c3 = MFMA(a0, Bs0[3][0], c3); c3 = MFMA(a1, Bs0[3][1], c3);
            ushort_t* sp = srcA + (size_t)nd * 2048 + n16 * 16 + q * 4;
            st4(sp, c0); st4(sp + 256, c1); st4(sp + 512, c2); st4(sp + 768, c3);
        }
        {
            floatx4 c0 = zero, c1 = zero, c2 = zero, c3 = zero;
            c0 = MFMA(a0, Bs1[0][0], c0); c0 = MFMA(a1, Bs1[0][1], c0);
            c1 = MFMA(a0, Bs1[1][0], c1); c1 = MFMA(a1, Bs1[1][1], c1);
            c2 = MFMA(a0, Bs1[2][0], c2); c2 = MFMA(a1, Bs1[2][1], c2);
            c3 = MFMA(a0, Bs1[3][0], c3); c3 = MFMA(a1, Bs1[3][1], c3);
            ushort_t* sp = srcA + (size_t)nd * 2048 + 1024 + n16 * 16 + q * 4;
            st4(sp, c0); st4(sp + 256, c1); st4(sp + 512, c2); st4(sp + 768, c3);
        }
        {
            floatx4 c0 = zero, c1 = zero, c2 = zero, c3 = zero;
            if (rsel) {
                c0 = MFMA(a0, Bt1[0][0], c0); c0 = MFMA(a1, Bt1[0][1], c0);
                c1 = MFMA(a0, Bt1[1][0], c1); c1 = MFMA(a1, Bt1[1][1], c1);
                c2 = MFMA(a0, Bt1[2][0], c2); c2 = MFMA(a1, Bt1[2][1], c2);
                c3 = MFMA(a0, Bt1[3][0], c3); c3 = MFMA(a1, Bt1[3][1], c3);
            } else {
                c0 = MFMA(a0, Bt0[0][0], c0); c0 = MFMA(a1, Bt0[0][1], c0);
                c1 = MFMA(a0, Bt0[1][0], c1); c1 = MFMA(a1, Bt0[1][1], c1);
                c2 = MFMA(a0, Bt0[2][0], c2); c2 = MFMA(a1, Bt0[2][1], c2);
                c3 = MFMA(a0, Bt0[3][0], c3); c3 = MFMA(a1, Bt0[3][1], c3);
            }
            ushort_t* tp = tgtA + (size_t)nd * 1024 + n16 * 16 + q * 4;
            st4(tp, c0); st4(tp + 256, c1); st4(tp + 512, c2); st4(tp + 768, c3);
        }
        {
            floatx4 cp = zero;
            cp = MFMA(a0, Bp[0], cp); cp = MFMA(a1, Bp[1], cp);
            if (q == 0) {
                int r = n16 >> 3, h = n16 & 7;
                float* pp = psrc + (size_t)nd * 48 + r * 24 + h;
                pp[0]  = cp[1];
                pp[8]  = cp[2];
                pp[16] = cp[3];
            }
            floatx4 cq = zero;
            cq = MFMA(a0, Bq[0], cq); cq = MFMA(a1, Bq[1], cq);
            if (q == 0 && (n16 >> 3) == rsel) {
                int h = n16 & 7;
                float* pp = ptgt + (size_t)nd * 24 + h;
                pp[0]  = cq[1];
                pp[8]  = cq[2];
                pp[16] = cq[3];
            }
        }
    }
}

// ---------------------------------------------------------------------------
// Kernel C (fused): per-edge logits + exp + den/num scatter.
// ONE edge per wave, 256-thr blocks, 44 VGPR — the verified local optimum.
// Axes tested and rejected: 2-edge ILP (R3 +21us), persistent+prefetch
// (R9 +36us), 1024-thr blocks (R10 +15us), dst-sort variants (R5/R6/R11
// +8..+106us). Latency/issue-balanced: VALU 40%, occ 48%, HBM 24%.
// ---------------------------------------------------------------------------
__global__ __launch_bounds__(256) void k_fused(
    const int* __restrict__ ei, const float* __restrict__ dist,
    const int* __restrict__ zn, const int* __restrict__ mask,
    const float* __restrict__ wig, const float* __restrict__ cmp,
    const float* __restrict__ embs0, const float* __restrict__ embt0, const float* __restrict__ wd0,
    const float* __restrict__ embs1, const float* __restrict__ embt1, const float* __restrict__ wd1,
    const float* __restrict__ va0, const float* __restrict__ va1,
    const ushort_t* __restrict__ srcA, const ushort_t* __restrict__ tgtA,
    const float* __restrict__ psrc, const float* __restrict__ ptgt,
    float* __restrict__ den, float* __restrict__ num, int E)
{
    int wv = threadIdx.x >> 6, j = threadIdx.x & 63;
    int e = blockIdx.x * 4 + wv;
    if (e >= E) return;
    int src = ei[e], dst = ei[E + e];
    int r = (mask[dst] != 0);
    float d = dist[e];
    int zs = zn[src], zt = zn[dst];
    int hq = j >> 3, h8 = j & 7;

    // issue all gathers up front (overlap latency with the ce loop)
    const float* w0 = wig + (size_t)e * 256;            // D[0, :]
    float4 wA = *(const float4*)(w0);
    float4 wB = *(const float4*)(w0 + 4);
    float4 wC = *(const float4*)(w0 + 8);
    float4 wD = *(const float4*)(w0 + 12);
    const ushort_t* sa = srcA + (size_t)src * 2048 + r * 1024 + j * 16;
    const ushort_t* ta = tgtA + (size_t)dst * 1024 + j * 16;
    short8 sv0 = *(const short8*)(sa);       // rows 0..7 of col j
    short8 sv1 = *(const short8*)(sa + 8);   // rows 8..15
    short8 tv0 = *(const short8*)(ta);
    short8 tv1 = *(const short8*)(ta + 8);
    float pv = 0.f;
    if (h8 < 3)
        pv = psrc[(size_t)src * 48 + r * 24 + h8 * 8 + hq]
           + ptgt[(size_t)dst * 24 + h8 * 8 + hq];

    // edge scalar embedding (32 values via j&31)
    float es;
    {
        int ce = j & 31;
        float z = r ? (d * wd1[ce] + embs1[zs * 32 + ce] + embt1[zt * 32 + ce])
                    : (d * wd0[ce] + embs0[zs * 32 + ce] + embt0[zt * 32 + ce]);
        es = z / (1.f + __expf(-z));   // silu
    }

    const float* WeWa   = cmp + r * RS + 8192;
    const float* WeWvWo = cmp + r * RS + 11264;
    float f0a = 0.f, ej = 0.f;
    #pragma unroll
    for (int ce = 0; ce < 32; ++ce) {
        float ev = __shfl(es, ce, 64);
        f0a += ev * WeWa[ce * 64 + j];
        ej  += ev * WeWvWo[ce * 8 + hq];
    }

    // f0a[j] += sum_n D[0,n] * (ysa[src][n,j] + yta[dst][n,j]) : in-lane
    f0a += wA.x * (bf2f((ushort_t)sv0[0]) + bf2f((ushort_t)tv0[0]));
    f0a += wA.y * (bf2f((ushort_t)sv0[1]) + bf2f((ushort_t)tv0[1]));
    f0a += wA.z * (bf2f((ushort_t)sv0[2]) + bf2f((ushort_t)tv0[2]));
    f0a += wA.w * (bf2f((ushort_t)sv0[3]) + bf2f((ushort_t)tv0[3]));
    f0a += wB.x * (bf2f((ushort_t)sv0[4]) + bf2f((ushort_t)tv0[4]));
    f0a += wB.y * (bf2f((ushort_t)sv0[5]) + bf2f((ushort_t)tv0[5]));
    f0a += wB.z * (bf2f((ushort_t)sv0[6]) + bf2f((ushort_t)tv0[6]));
    f0a += wB.w * (bf2f((ushort_t)sv0[7]) + bf2f((ushort_t)tv0[7]));
    f0a += wC.x * (bf2f((ushort_t)sv1[0]) + bf2f((ushort_t)tv1[0]));
    f0a += wC.y * (bf2f((ushort_t)sv1[1]) + bf2f((ushort_t)tv1[1]));
    f0a += wC.z * (bf2f((ushort_t)sv1[2]) + bf2f((ushort_t)tv1[2]));
    f0a += wC.w * (bf2f((ushort_t)sv1[3]) + bf2f((ushort_t)tv1[3]));
    f0a += wD.x * (bf2f((ushort_t)sv1[4]) + bf2f((ushort_t)tv1[4]));
    f0a += wD.y * (bf2f((ushort_t)sv1[5]) + bf2f((ushort_t)tv1[5]));
    f0a += wD.z * (bf2f((ushort_t)sv1[6]) + bf2f((ushort_t)tv1[6]));
    f0a += wD.w * (bf2f((ushort_t)sv1[7]) + bf2f((ushort_t)tv1[7]));

    float la = f0a > 0.f ? f0a : 0.2f * f0a;           // leaky_relu(0.2)
    float val = la * (r ? va1[j] : va0[j]);
    val += __shfl_xor(val, 1);
    val += __shfl_xor(val, 2);
    val += __shfl_xor(val, 4);                          // logit per 8-lane group
    float ex = __expf(val);                             // no-max softmax (logits bounded)

    if (h8 == 0) atomicAdd(&den[dst * 8 + hq], ex);
    if (h8 < 3) {
        float w0k = (h8 == 0) ? wA.y : (h8 == 1) ? wA.z : wA.w;  // D[0,1..3]
        atomicAdd(&num[dst * 24 + hq * 3 + h8], ex * (pv + ej * w0k));
    }
}

// ---------------------------------------------------------------------------
// Kernel D: out[n,k] = sum_h num[n,h,k]/(den[n,h]+eps). Writes every element.
// ---------------------------------------------------------------------------
__global__ __launch_bounds__(256) void k_out(
    const float* __restrict__ num, const float* __restrict__ den,
    float* __restrict__ out, int N3)
{
    int t = blockIdx.x * 256 + threadIdx.x;
    if (t >= N3) return;
    int n = t / 3, k = t - n * 3;
    float acc = 0.f;
    #pragma unroll
    for (int h = 0; h < 8; ++h)
        acc += num[n * 24 + h * 3 + k] / (den[n * 8 + h] + 1e-9f);
    out[t] = acc;
}

// ---------------------------------------------------------------------------
extern "C" void kernel_launch(void* const* d_in, const int* in_sizes, int n_in,
                              void* d_out, int out_size, void* d_ws, size_t ws_size,
                              hipStream_t stream) {
    const float* x    = (const float*)d_in[0];
    const int*   zn   = (const int*)d_in[1];
    const float* dist = (const float*)d_in[2];
    const int*   ei   = (const int*)d_in[3];
    const int*   mask = (const int*)d_in[4];
    const float* wig  = (const float*)d_in[5];
    const float* fs[10]; const float* dn[10];
    for (int i = 0; i < 10; ++i) { fs[i] = (const float*)d_in[6 + i]; dn[i] = (const float*)d_in[16 + i]; }

    int N = in_sizes[1];   // atomic_numbers count
    int E = in_sizes[2];   // edge_distance count

    // workspace carve-up
    float* cmp  = (float*)d_ws;                    // 2*RS = 23040 floats
    float* den  = cmp + 2 * RS;                    // N*8
    float* num  = den + (size_t)N * 8;             // N*24
    float* psrc = num + (size_t)N * 24;            // N*48
    float* ptgt = psrc + (size_t)N * 48;           // N*24
    ushort_t* srcA = (ushort_t*)(ptgt + (size_t)N * 24);  // N*2048 bf16
    ushort_t* tgtA = srcA + (size_t)N * 2048;             // N*1024 bf16
    ushort_t* packW = tgtA + (size_t)N * 1024;            // 16384 ushorts
    // total ~26.3 MB

    // NOTE: no memsets — k_node zeroes den/num, k_out writes all of d_out.

    k_composites<<<dim3(6, 2, 4), 256, 0, stream>>>(
        fs[4], fs[5], fs[3], fs[6], fs[8], fs[9],
        dn[4], dn[5], dn[3], dn[6], dn[8], dn[9], cmp, packW);

    int nodeBlocks = 1000;                       // 4000 waves -> 1 node/wave
    int totWaves = nodeBlocks * 4;
    k_node<<<nodeBlocks, 256, 0, stream>>>(x, mask, cmp, packW, psrc, ptgt,
                                           srcA, tgtA, den, num, N, totWaves);

    k_fused<<<(E + 3) / 4, 256, 0, stream>>>(
        ei, dist, zn, mask, wig, cmp,
        fs[0], fs[1], fs[2], dn[0], dn[1], dn[2],
        fs[7], dn[7], srcA, tgtA, psrc, ptgt, den, num, E);

    k_out<<<(N * 3 + 255) / 256, 256, 0, stream>>>(num, den, (float*)d_out, N * 3);
}